// Round 11
// baseline (735.587 us; speedup 1.0000x reference)
//
#include <hip/hip_runtime.h>
#include <math.h>
#include <float.h>

#define BNS_C 0.9999950000374996f /* 1/sqrt(1+1e-5) */

typedef __bf16 bf8 __attribute__((ext_vector_type(8)));
typedef float f4 __attribute__((ext_vector_type(4)));
union I4BF8 { int4 i; bf8 b; };

static __device__ __forceinline__ unsigned short f2bf(float f) {
    unsigned u = __float_as_uint(f);
    u += 0x7fff + ((u >> 16) & 1);          // round-to-nearest-even
    return (unsigned short)(u >> 16);
}

// ------- x[b][6][1024] -> X0[b][n][8] (zero-padded) + xx norms -------
__global__ void k_xin_t(const float* __restrict__ x, float* __restrict__ X0, float* __restrict__ xx) {
    int i = blockIdx.x * 256 + threadIdx.x;   // over 16384 points
    int b = i >> 10, n = i & 1023;
    const float* xb = x + (((size_t)b * 6) << 10) + n;
    float4* o4 = (float4*)(X0 + ((size_t)i << 3));
    float v0 = xb[0], v1 = xb[1 << 10], v2 = xb[2 << 10];
    float v3 = xb[3 << 10], v4 = xb[4 << 10], v5 = xb[5 << 10];
    o4[0] = make_float4(v0, v1, v2, v3);
    o4[1] = make_float4(v4, v5, 0.f, 0.f);
    xx[i] = v0*v0 + v1*v1 + v2*v2 + v3*v3 + v4*v4 + v5*v5;
}

// ------- w5 f32 [1024][512] -> bf16 [1024][512] (once per launch) -------
__global__ void k_w5b(const float* __restrict__ w5, unsigned short* __restrict__ W5B) {
    int i = blockIdx.x * 256 + threadIdx.x;   // 65536 threads x 8 floats
    const float4* src = (const float4*)(w5 + (size_t)i * 8);
    float4 f0 = src[0], f1 = src[1];
    I4BF8 u_;
    u_.i.x = f2bf(f0.x) | ((unsigned)f2bf(f0.y) << 16);
    u_.i.y = f2bf(f0.z) | ((unsigned)f2bf(f0.w) << 16);
    u_.i.z = f2bf(f1.x) | ((unsigned)f2bf(f1.y) << 16);
    u_.i.w = f2bf(f1.z) | ((unsigned)f2bf(f1.w) << 16);
    *(int4*)(W5B + (size_t)i * 8) = u_.i;
}

// ---- FUSED gram + top-20, v2: D never touches global (r8 showed gram time is
// Cp-INDEPENDENT = D-write-bound; D round-trip ~260us). r9's version spilled
// (array accs live across select barriers -> scratch, rule #20). Fixes here:
//   1. 64 accumulators are NAMED SCALARS (the r3 fix that cured k_final_mfma).
//   2. Per row: keys written to LDS KEYS[wv][1024] (that row's accs die there);
//      radix-select reads keys from LDS per pass -> no key array in registers.
//   3. Histograms alias the CP staging region AFTER a block barrier (CP dead).
//   4. No launch_bounds cap (r9's (256,4)=128-VGPR cap fed the spill).
// D values bit-identical: c-ascending single-acc FMA, (2a - xn) - xm epilogue.
// Block = 16 rows x 1024 cols x one batch; wave owns 4 rows; lane owns cols
// lane+64k. Grid 1024, XCD-bijective (batch pair per XCD -> X L2-resident).
#define WSYNC() asm volatile("s_waitcnt lgkmcnt(0)" ::: "memory")
__global__ __launch_bounds__(256) void k_gtk(const float* __restrict__ X, const float* __restrict__ xx,
                                             int* __restrict__ idxo, int Cp) {
    __shared__ float CP[8 * 1028];           // [cc][col] col-panel, 32.9 KB
    __shared__ float RX[128];                // [cc][16] row-panel
    __shared__ unsigned KEYS[4][1024];       // per-wave one row's keys, 16 KB
    __shared__ int CNT[4];
    unsigned* H = (unsigned*)CP;             // select-phase histograms alias CP

    int g = blockIdx.x;                      // 0..1023
    int b = ((g & 7) << 1) + (g >> 9);       // XCD g%8 -> batches {2p, 2p+1}
    int n0 = ((g >> 3) & 63) << 4;
    int tid = threadIdx.x, lane = tid & 63, wv = tid >> 6;
    int rep = lane & 3;
    const float* Xb = X + (((size_t)b) << 10) * Cp;
    const float* xxb = xx + (b << 10);

    float A0_0=0.f,A0_1=0.f,A0_2=0.f,A0_3=0.f,A0_4=0.f,A0_5=0.f,A0_6=0.f,A0_7=0.f,
          A0_8=0.f,A0_9=0.f,A0_10=0.f,A0_11=0.f,A0_12=0.f,A0_13=0.f,A0_14=0.f,A0_15=0.f;
    float A1_0=0.f,A1_1=0.f,A1_2=0.f,A1_3=0.f,A1_4=0.f,A1_5=0.f,A1_6=0.f,A1_7=0.f,
          A1_8=0.f,A1_9=0.f,A1_10=0.f,A1_11=0.f,A1_12=0.f,A1_13=0.f,A1_14=0.f,A1_15=0.f;
    float A2_0=0.f,A2_1=0.f,A2_2=0.f,A2_3=0.f,A2_4=0.f,A2_5=0.f,A2_6=0.f,A2_7=0.f,
          A2_8=0.f,A2_9=0.f,A2_10=0.f,A2_11=0.f,A2_12=0.f,A2_13=0.f,A2_14=0.f,A2_15=0.f;
    float A3_0=0.f,A3_1=0.f,A3_2=0.f,A3_3=0.f,A3_4=0.f,A3_5=0.f,A3_6=0.f,A3_7=0.f,
          A3_8=0.f,A3_9=0.f,A3_10=0.f,A3_11=0.f,A3_12=0.f,A3_13=0.f,A3_14=0.f,A3_15=0.f;

    int nCh = Cp >> 3;
    for (int ch = 0; ch < nCh; ++ch) {
        int c0 = ch << 3;
        __syncthreads();                     // prev chunk's reads done
#pragma unroll
        for (int s = 0; s < 4; ++s) {        // stage col-panel
            int col = tid + (s << 8);
            const float* xp = Xb + (size_t)col * Cp + c0;
            float4 f0 = *(const float4*)xp;
            float4 f1 = *(const float4*)(xp + 4);
            CP[0 * 1028 + col] = f0.x; CP[1 * 1028 + col] = f0.y;
            CP[2 * 1028 + col] = f0.z; CP[3 * 1028 + col] = f0.w;
            CP[4 * 1028 + col] = f1.x; CP[5 * 1028 + col] = f1.y;
            CP[6 * 1028 + col] = f1.z; CP[7 * 1028 + col] = f1.w;
        }
        if (tid < 16) {                      // stage row-panel
            const float* xp = Xb + (size_t)(n0 + tid) * Cp + c0;
            float4 f0 = *(const float4*)xp;
            float4 f1 = *(const float4*)(xp + 4);
            RX[0 * 16 + tid] = f0.x; RX[1 * 16 + tid] = f0.y;
            RX[2 * 16 + tid] = f0.z; RX[3 * 16 + tid] = f0.w;
            RX[4 * 16 + tid] = f1.x; RX[5 * 16 + tid] = f1.y;
            RX[6 * 16 + tid] = f1.z; RX[7 * 16 + tid] = f1.w;
        }
        __syncthreads();                     // panel visible
#pragma unroll
        for (int cj = 0; cj < 8; ++cj) {
            const float* cpj = CP + cj * 1028;
            float rv0 = RX[cj * 16 + (wv << 2) + 0];
            float rv1 = RX[cj * 16 + (wv << 2) + 1];
            float rv2 = RX[cj * 16 + (wv << 2) + 2];
            float rv3 = RX[cj * 16 + (wv << 2) + 3];
#define FMAK(K) { float cv_ = cpj[lane + (K << 6)]; \
    A0_##K += rv0 * cv_; A1_##K += rv1 * cv_; A2_##K += rv2 * cv_; A3_##K += rv3 * cv_; }
            FMAK(0) FMAK(1) FMAK(2) FMAK(3) FMAK(4) FMAK(5) FMAK(6) FMAK(7)
            FMAK(8) FMAK(9) FMAK(10) FMAK(11) FMAK(12) FMAK(13) FMAK(14) FMAK(15)
#undef FMAK
        }
    }
    __syncthreads();                         // CP dead -> histograms may alias it

    unsigned* Hw = H + (wv << 10);

#define KEYW(K, AR) { float d_ = (2.f * (AR) - xr_) - xxb[lane + (K << 6)]; \
    unsigned u_ = __float_as_uint(d_); \
    KEYS[wv][(K << 6) + lane] = u_ ^ ((unsigned)(((int)u_) >> 31) | 0x80000000u); }

#define SELROW(R) { \
    float xr_ = xxb[n0 + (wv << 2) + (R)]; \
    KEYW(0, A##R##_0) KEYW(1, A##R##_1) KEYW(2, A##R##_2) KEYW(3, A##R##_3) \
    KEYW(4, A##R##_4) KEYW(5, A##R##_5) KEYW(6, A##R##_6) KEYW(7, A##R##_7) \
    KEYW(8, A##R##_8) KEYW(9, A##R##_9) KEYW(10, A##R##_10) KEYW(11, A##R##_11) \
    KEYW(12, A##R##_12) KEYW(13, A##R##_13) KEYW(14, A##R##_14) KEYW(15, A##R##_15) \
    unsigned long long pfx = 0, thresh = 0; \
    int shift = 56, kneed = 20, tshift = 0; \
    for (;;) { \
        _Pragma("unroll") for (int z = 0; z < 16; ++z) Hw[lane + (z << 6)] = 0u; \
        WSYNC(); \
        if (shift == 56) { \
            _Pragma("unroll") for (int j = 0; j < 16; ++j) { \
                unsigned s_ = KEYS[wv][(j << 6) + lane]; \
                atomicAdd(&Hw[((s_ >> 24) & 255u) * 4 + rep], 1u); } \
        } else { \
            _Pragma("unroll") for (int j = 0; j < 16; ++j) { \
                unsigned s_ = KEYS[wv][(j << 6) + lane]; \
                unsigned long long kj = (((unsigned long long)s_) << 32) | (unsigned)(1023 - (lane + (j << 6))); \
                if ((kj >> (shift + 8)) == pfx) \
                    atomicAdd(&Hw[((unsigned)(kj >> shift) & 255u) * 4 + rep], 1u); } \
        } \
        WSYNC(); \
        int bTop = 255 - 4 * lane; \
        uint4 r0 = *(const uint4*)(Hw + (bTop    ) * 4); \
        uint4 r1 = *(const uint4*)(Hw + (bTop - 1) * 4); \
        uint4 r2 = *(const uint4*)(Hw + (bTop - 2) * 4); \
        uint4 r3 = *(const uint4*)(Hw + (bTop - 3) * 4); \
        int h0 = (int)(r0.x + r0.y + r0.z + r0.w); \
        int h1 = (int)(r1.x + r1.y + r1.z + r1.w); \
        int h2 = (int)(r2.x + r2.y + r2.z + r2.w); \
        int h3 = (int)(r3.x + r3.y + r3.z + r3.w); \
        int s4 = h0 + h1 + h2 + h3; \
        int inc = s4; \
        _Pragma("unroll") for (int off = 1; off < 64; off <<= 1) { \
            int y_ = __shfl_up(inc, off); \
            if (lane >= off) inc += y_; } \
        int pre = inc - s4; \
        bool qual = (pre < kneed) && (inc >= kneed); \
        unsigned long long qm = __ballot(qual); \
        int src = __ffsll((unsigned long long)qm) - 1; \
        int bsel = 0, above = 0, cntb = 0; \
        if (qual) { \
            int c1 = pre + h0, c2 = c1 + h1, c3 = c2 + h2; \
            if (c1 >= kneed)      { bsel = bTop;     above = pre; cntb = h0; } \
            else if (c2 >= kneed) { bsel = bTop - 1; above = c1;  cntb = h1; } \
            else if (c3 >= kneed) { bsel = bTop - 2; above = c2;  cntb = h2; } \
            else                  { bsel = bTop - 3; above = c3;  cntb = h3; } \
        } \
        bsel  = __shfl(bsel, src); \
        above = __shfl(above, src); \
        cntb  = __shfl(cntb, src); \
        if (above + cntb == kneed) { thresh = (pfx << 8) | (unsigned)bsel; tshift = shift; break; } \
        kneed -= above; \
        pfx = (pfx << 8) | (unsigned)bsel; \
        shift -= 8; \
    } \
    if (lane == 0) CNT[wv] = 0; \
    WSYNC(); \
    int* outp = idxo + (size_t)((b << 10) + n0 + (wv << 2) + (R)) * 20; \
    _Pragma("unroll") for (int j = 0; j < 16; ++j) { \
        unsigned s_ = KEYS[wv][(j << 6) + lane]; \
        unsigned long long kj = (((unsigned long long)s_) << 32) | (unsigned)(1023 - (lane + (j << 6))); \
        if ((kj >> tshift) >= thresh) { \
            int p = atomicAdd(&CNT[wv], 1); \
            outp[p] = 1023 - (int)(kj & 1023u); } \
    } \
    WSYNC(); }

    SELROW(0)
    SELROW(1)
    SELROW(2)
    SELROW(3)
#undef SELROW
#undef KEYW
}
#undef WSYNC

// ---- V[b][n][o] = X·Wa^T, U[b][n][o] = X·(Wb-Wa)^T ; c-major LDS + reg prefetch ----
__global__ __launch_bounds__(256) void k_uv(const float* __restrict__ X, const float* __restrict__ w,
                                            float* __restrict__ V, float* __restrict__ U,
                                            int Cp, int C, int O) {
    int n0 = blockIdx.x * 64, o0 = blockIdx.y * 64, b = blockIdx.z;
    __shared__ float Xs[32 * 68], Was[32 * 68], Wds[32 * 68];
    int tid = threadIdx.x, ti = tid & 15, tj = tid >> 4;
    int scc = tid & 31, srow = tid >> 5;
    float accv[4][4] = {}, accu[4][4] = {};
    float px[8], pwa[8], pwd[8];
    const float* Xb = X + (((size_t)b) << 10) * Cp;
    int W2 = 2 * C;

    {   // prefetch K-slice 0
        int c = scc;
        const float* Xn = Xb + (size_t)(n0 + srow) * Cp + c;
        const float* Wr = w + (size_t)(o0 + srow) * W2 + c;
#pragma unroll
        for (int k2 = 0; k2 < 8; ++k2) {
            px[k2] = (c < Cp) ? Xn[(size_t)(k2 * 8) * Cp] : 0.f;
            float wa = 0.f, wd = 0.f;
            if (c < C) {
                float a_ = Wr[(size_t)(k2 * 8) * W2];
                float b_ = Wr[(size_t)(k2 * 8) * W2 + C];
                wa = a_; wd = b_ - a_;
            }
            pwa[k2] = wa; pwd[k2] = wd;
        }
    }
    for (int c0 = 0; c0 < Cp; c0 += 32) {
        __syncthreads();
#pragma unroll
        for (int k2 = 0; k2 < 8; ++k2) {
            Xs[scc * 68 + k2 * 8 + srow]  = px[k2];
            Was[scc * 68 + k2 * 8 + srow] = pwa[k2];
            Wds[scc * 68 + k2 * 8 + srow] = pwd[k2];
        }
        __syncthreads();
        if (c0 + 32 < Cp) {                  // prefetch next K-slice under the FMA block
            int c = c0 + 32 + scc;
            const float* Xn = Xb + (size_t)(n0 + srow) * Cp + c;
            const float* Wr = w + (size_t)(o0 + srow) * W2 + c;
#pragma unroll
            for (int k2 = 0; k2 < 8; ++k2) {
                px[k2] = (c < Cp) ? Xn[(size_t)(k2 * 8) * Cp] : 0.f;
                float wa = 0.f, wd = 0.f;
                if (c < C) {
                    float a_ = Wr[(size_t)(k2 * 8) * W2];
                    float b_ = Wr[(size_t)(k2 * 8) * W2 + C];
                    wa = a_; wd = b_ - a_;
                }
                pwa[k2] = wa; pwd[k2] = wd;
            }
        }
#pragma unroll 8
        for (int cc = 0; cc < 32; ++cc) {
            const float4 xv = *(const float4*)(Xs  + cc * 68 + 4 * tj);
            const float4 av = *(const float4*)(Was + cc * 68 + 4 * ti);
            const float4 dv = *(const float4*)(Wds + cc * 68 + 4 * ti);
            accv[0][0] += xv.x * av.x; accv[0][1] += xv.x * av.y; accv[0][2] += xv.x * av.z; accv[0][3] += xv.x * av.w;
            accv[1][0] += xv.y * av.x; accv[1][1] += xv.y * av.y; accv[1][2] += xv.y * av.z; accv[1][3] += xv.y * av.w;
            accv[2][0] += xv.z * av.x; accv[2][1] += xv.z * av.y; accv[2][2] += xv.z * av.z; accv[2][3] += xv.z * av.w;
            accv[3][0] += xv.w * av.x; accv[3][1] += xv.w * av.y; accv[3][2] += xv.w * av.z; accv[3][3] += xv.w * av.w;
            accu[0][0] += xv.x * dv.x; accu[0][1] += xv.x * dv.y; accu[0][2] += xv.x * dv.z; accu[0][3] += xv.x * dv.w;
            accu[1][0] += xv.y * dv.x; accu[1][1] += xv.y * dv.y; accu[1][2] += xv.y * dv.z; accu[1][3] += xv.y * dv.w;
            accu[2][0] += xv.z * dv.x; accu[2][1] += xv.z * dv.y; accu[2][2] += xv.z * dv.z; accu[2][3] += xv.z * dv.w;
            accu[3][0] += xv.w * dv.x; accu[3][1] += xv.w * dv.y; accu[3][2] += xv.w * dv.z; accu[3][3] += xv.w * dv.w;
        }
    }
#pragma unroll
    for (int a = 0; a < 4; ++a) {
        int n = n0 + 4 * tj + a;
        size_t base = ((size_t)((b << 10) + n)) * O + o0 + 4 * ti;
        *(float4*)(V + base) = make_float4(accv[a][0], accv[a][1], accv[a][2], accv[a][3]);
        *(float4*)(U + base) = make_float4(accu[a][0], accu[a][1], accu[a][2], accu[a][3]);
    }
}

// ---- float4-vectorized gmax: out[b][n][o] = max_k leaky(bn(V[m_k]+U[n])) ----
__global__ __launch_bounds__(256) void k_gmax4(const float* __restrict__ V, const float* __restrict__ U,
                                               const int* __restrict__ idx,
                                               const float* __restrict__ gg, const float* __restrict__ bb,
                                               float* __restrict__ Xo, float* __restrict__ xx,
                                               unsigned short* __restrict__ HB, int coff, int O, int Olog) {
    int tid = threadIdx.x;
    int L = O >> 2;                          // lanes per point
    int j = tid >> (Olog - 2);               // point slot in block
    int o4 = tid & (L - 1);
    int o = o4 << 2;
    int orig = blockIdx.x;                   // 16*O blocks
    int r = orig >> 3;
    int b = (orig & 7) + ((r >> Olog) << 3); // XCD class = b & 7
    int pg = r & ((1 << Olog) - 1);
    int n = (pg << (10 - Olog)) + j;
    int pt = (b << 10) + n;

    float4 uv = *(const float4*)(U + (size_t)pt * O + o);
    float4 gv = *(const float4*)(gg + o);
    float4 bv = *(const float4*)(bb + o);
    const int* ip = idx + (size_t)pt * 20;   // 80 B, 16B-aligned
    int4 i0 = *(const int4*)(ip);
    int4 i1 = *(const int4*)(ip + 4);
    int4 i2 = *(const int4*)(ip + 8);
    int4 i3 = *(const int4*)(ip + 12);
    int4 i4 = *(const int4*)(ip + 16);
    const float4* Vb = (const float4*)(V + ((size_t)(b << 10)) * O) + o4;

    float mx0 = -FLT_MAX, mx1 = -FLT_MAX, mx2 = -FLT_MAX, mx3 = -FLT_MAX;
#define GK(M) { int m_ = (M) & 1023; float4 vv = Vb[(size_t)m_ * L]; float y_; \
    y_ = gv.x * ((vv.x + uv.x) * BNS_C) + bv.x; y_ = fmaxf(y_, 0.2f * y_); mx0 = fmaxf(mx0, y_); \
    y_ = gv.y * ((vv.y + uv.y) * BNS_C) + bv.y; y_ = fmaxf(y_, 0.2f * y_); mx1 = fmaxf(mx1, y_); \
    y_ = gv.z * ((vv.z + uv.z) * BNS_C) + bv.z; y_ = fmaxf(y_, 0.2f * y_); mx2 = fmaxf(mx2, y_); \
    y_ = gv.w * ((vv.w + uv.w) * BNS_C) + bv.w; y_ = fmaxf(y_, 0.2f * y_); mx3 = fmaxf(mx3, y_); }
    GK(i0.x) GK(i0.y) GK(i0.z) GK(i0.w)
    GK(i1.x) GK(i1.y) GK(i1.z) GK(i1.w)
    GK(i2.x) GK(i2.y) GK(i2.z) GK(i2.w)
    GK(i3.x) GK(i3.y) GK(i3.z) GK(i3.w)
    GK(i4.x) GK(i4.y) GK(i4.z) GK(i4.w)
#undef GK

    if (Xo) *(float4*)(Xo + (size_t)pt * O + o) = make_float4(mx0, mx1, mx2, mx3);

    int c = coff + o;                        // o % 4 == 0 -> 4 contiguous within a 32-slice
    union { int2 i2v; unsigned short u[4]; } pk;
    pk.u[0] = f2bf(mx0); pk.u[1] = f2bf(mx1); pk.u[2] = f2bf(mx2); pk.u[3] = f2bf(mx3);
    *(int2*)(HB + (((size_t)(b * 16 + (c >> 5)) << 10) + n) * 32 + (c & 31)) = pk.i2v;

    if (Xo) {
        float s = mx0 * mx0 + mx1 * mx1 + mx2 * mx2 + mx3 * mx3;
        for (int off = L >> 1; off; off >>= 1) s += __shfl_down(s, off, L);
        if (o4 == 0) xx[pt] = s;
    }
}

// ------- fused MFMA GEMM + BN/leaky + partial max/sum pool, LDS-tiled 128x128 -------
// NAMED-SCALAR register state (array forms spilled to scratch in r1-r2).
__global__ __launch_bounds__(256, 2) void k_final_mfma(const unsigned short* __restrict__ HB,
                                                       const unsigned short* __restrict__ W5B,
                                                       const float* __restrict__ g5,
                                                       const float* __restrict__ b5,
                                                       float* __restrict__ pp) {
    __shared__ __align__(16) unsigned short As[128 * 64];
    __shared__ __align__(16) unsigned short Bs[128 * 64];
    __shared__ float Lm[2][128], Ls[2][128];
    int rb = blockIdx.x;                     // 0..127 : b = rb>>3, n0 = (rb&7)*128
    int o0 = blockIdx.y << 7;                // 0..896
    int b  = rb >> 3, n0 = (rb & 7) << 7;
    int tid = threadIdx.x, lane = tid & 63, wv = tid >> 6;
    int wm = wv >> 1, wn = wv & 1;
    int wm64 = wm << 6, wn64 = wn << 6;
    int ti = lane & 15, tq = lane >> 4;
    int srow = lane >> 3;                    // 0..7 (row within 8-row segment)
    int sch  = lane & 7;                     // chunk 0..7 (8 ush = 16 B each)
    int wch  = (sch ^ srow) << 3;            // swizzled write chunk offset (ushorts)

    const unsigned short* Abase = HB + ((((size_t)(b * 16 + (sch >> 2))) << 10) + n0) * 32 + (sch & 3) * 8;
    const unsigned short* Bbase = W5B + (size_t)o0 * 512 + sch * 8;

    f4 c00 = {0.f,0.f,0.f,0.f}, c01 = c00, c02 = c00, c03 = c00;
    f4 c10 = c00, c11 = c00, c12 = c00, c13 = c00;
    f4 c20 = c00, c21 = c00, c22 = c00, c23 = c00;
    f4 c30 = c00, c31 = c00, c32 = c00, c33 = c00;

    int4 ar0, ar1, ar2, ar3, br0, br1, br2, br3;

#define PF(AR, BR, J, IT) { int rA_ = ((J) * 4 + wv) * 8 + srow; \
    AR = *(const int4*)(Abase + ((size_t)(IT) << 16) + (size_t)rA_ * 32); \
    BR = *(const int4*)(Bbase + (size_t)rA_ * 512 + (IT) * 64); }
#define ST(AR, BR, J) { int rA_ = ((J) * 4 + wv) * 8 + srow; \
    *(int4*)(As + rA_ * 64 + wch) = AR; *(int4*)(Bs + rA_ * 64 + wch) = BR; }
#define FRAG_LD(AV, BV, F) { I4BF8 uA_, uB_; \
    uA_.i = *(const int4*)(As + (wm64 + (F) * 16 + ti) * 64 + co); \
    uB_.i = *(const int4*)(Bs + (wn64 + (F) * 16 + ti) * 64 + co); \
    AV = uA_.b; BV = uB_.b; }
#define MM(CV, AV, BV) CV = __builtin_amdgcn_mfma_f32_16x16x32_bf16(AV, BV, CV, 0, 0, 0);

    PF(ar0, br0, 0, 0) PF(ar1, br1, 1, 0) PF(ar2, br2, 2, 0) PF(ar3, br3, 3, 0)
    for (int it = 0; it < 8; ++it) {
        __syncthreads();                      // prev iter's ds_reads done
        ST(ar0, br0, 0) ST(ar1, br1, 1) ST(ar2, br2, 2) ST(ar3, br3, 3)
        __syncthreads();                      // tile visible
        if (it < 7) {
            PF(ar0, br0, 0, it + 1) PF(ar1, br1, 1, it + 1)
            PF(ar2, br2, 2, it + 1) PF(ar3, br3, 3, it + 1)
        }
#pragma unroll
        for (int kk = 0; kk < 2; ++kk) {
            int co = (((kk * 4 + tq)) ^ (ti & 7)) << 3;   // swizzled read chunk
            bf8 a0, a1, a2, a3, p0, p1, p2, p3;
            FRAG_LD(a0, p0, 0) FRAG_LD(a1, p1, 1) FRAG_LD(a2, p2, 2) FRAG_LD(a3, p3, 3)
            MM(c00, a0, p0) MM(c01, a0, p1) MM(c02, a0, p2) MM(c03, a0, p3)
            MM(c10, a1, p0) MM(c11, a1, p1) MM(c12, a1, p2) MM(c13, a1, p3)
            MM(c20, a2, p0) MM(c21, a2, p1) MM(c22, a2, p2) MM(c23, a2, p3)
            MM(c30, a3, p0) MM(c31, a3, p1) MM(c32, a3, p2) MM(c33, a3, p3)
        }
    }
#undef PF
#undef ST
#undef FRAG_LD
#undef MM

    float gb0 = g5[o0 + wn64 +  0 + ti] * BNS_C, bv0 = b5[o0 + wn64 +  0 + ti];
    float gb1 = g5[o0 + wn64 + 16 + ti] * BNS_C, bv1 = b5[o0 + wn64 + 16 + ti];
    float gb2 = g5[o0 + wn64 + 32 + ti] * BNS_C, bv2 = b5[o0 + wn64 + 32 + ti];
    float gb3 = g5[o0 + wn64 + 48 + ti] * BNS_C, bv3 = b5[o0 + wn64 + 48 + ti];
    float mx0 = -FLT_MAX, mx1 = -FLT_MAX, mx2 = -FLT_MAX, mx3 = -FLT_MAX;
    float sm0 = 0.f, sm1 = 0.f, sm2 = 0.f, sm3 = 0.f;

#define EPI(CV, GB, BV, MX, SM) { \
    float y_; \
    y_ = GB * CV[0] + BV; y_ = y_ > 0.f ? y_ : 0.2f * y_; MX = fmaxf(MX, y_); SM += y_; \
    y_ = GB * CV[1] + BV; y_ = y_ > 0.f ? y_ : 0.2f * y_; MX = fmaxf(MX, y_); SM += y_; \
    y_ = GB * CV[2] + BV; y_ = y_ > 0.f ? y_ : 0.2f * y_; MX = fmaxf(MX, y_); SM += y_; \
    y_ = GB * CV[3] + BV; y_ = y_ > 0.f ? y_ : 0.2f * y_; MX = fmaxf(MX, y_); SM += y_; }

    EPI(c00, gb0, bv0, mx0, sm0) EPI(c10, gb0, bv0, mx0, sm0)
    EPI(c20, gb0, bv0, mx0, sm0) EPI(c30, gb0, bv0, mx0, sm0)
    EPI(c01, gb1, bv1, mx1, sm1) EPI(c11, gb1, bv1, mx1, sm1)
    EPI(c21, gb1, bv1, mx1, sm1) EPI(c31, gb1, bv1, mx1, sm1)
    EPI(c02, gb2, bv2, mx2, sm2) EPI(c12, gb2, bv2, mx2, sm2)
    EPI(c22, gb2, bv2, mx2, sm2) EPI(c32, gb2, bv2, mx2, sm2)
    EPI(c03, gb3, bv3, mx3, sm3) EPI(c13, gb3, bv3, mx3, sm3)
    EPI(c23, gb3, bv3, mx3, sm3) EPI(c33, gb3, bv3, mx3, sm3)
#undef EPI

#define RED(MX, SM, F) { \
    float m_ = MX, s_ = SM; \
    m_ = fmaxf(m_, __shfl_down(m_, 32)); s_ += __shfl_down(s_, 32); \
    m_ = fmaxf(m_, __shfl_down(m_, 16)); s_ += __shfl_down(s_, 16); \
    if (tq == 0) { Lm[wm][wn64 + (F) * 16 + ti] = m_; Ls[wm][wn64 + (F) * 16 + ti] = s_; } }
    RED(mx0, sm0, 0) RED(mx1, sm1, 1) RED(mx2, sm2, 2) RED(mx3, sm3, 3)
#undef RED

    __syncthreads();
    if (tid < 128) {
        float m_ = fmaxf(Lm[0][tid], Lm[1][tid]);
        float s_ = Ls[0][tid] + Ls[1][tid];
        float* pb = pp + (size_t)rb * 2048;
        pb[o0 + tid] = m_;
        pb[1024 + o0 + tid] = s_;
    }
}

// ---- wl1 FC fused with the row-block partial reduction (8 partials of 128 rows) ----
__global__ __launch_bounds__(256) void k_fc2p(const float* __restrict__ pp, const float* __restrict__ w,
                                              const float* __restrict__ gg, const float* __restrict__ bb,
                                              float* __restrict__ out, int O) {
    int gw = blockIdx.x * 4 + (threadIdx.x >> 6);
    int lane = threadIdx.x & 63;
    int r = gw / O, o = gw - r * O;
    const float* wr = w + (size_t)o * 2048;
    const float* q0 = pp + (size_t)r * 8 * 2048;
    float s = 0.f;
    for (int c = lane; c < 2048; c += 64) {
        float v;
        if (c < 1024) {
            v = q0[c];
#pragma unroll
            for (int t = 1; t < 8; ++t) v = fmaxf(v, q0[t * 2048 + c]);
        } else {
            v = 0.f;
#pragma unroll
            for (int t = 0; t < 8; ++t) v += q0[t * 2048 + c];
            v *= (1.f / 1024.f);
        }
        s += v * wr[c];
    }
#pragma unroll
    for (int off = 32; off; off >>= 1) s += __shfl_down(s, off);
    if (lane == 0) {
        float y = gg[o] * (s * BNS_C) + bb[o];
        out[gw] = y > 0.f ? y : 0.2f * y;
    }
}

// ------- FC tail: one block per batch row, wave-per-output, coalesced weight loads -------
__global__ __launch_bounds__(256) void k_fc_tail(const float* __restrict__ z1,
                                                 const float* __restrict__ wl2, const float* __restrict__ g7, const float* __restrict__ b7,
                                                 const float* __restrict__ wl21,
                                                 const float* __restrict__ wl22, const float* __restrict__ g8, const float* __restrict__ b8,
                                                 const float* __restrict__ wl3,
                                                 float* __restrict__ out) {
    __shared__ float L1[128], L2[64], L3[32];
    int r = blockIdx.x;
    int tid = threadIdx.x, lane = tid & 63, wv = tid >> 6;
    const float* ir = z1 + r * 256;
    float a0 = ir[lane], a1 = ir[lane + 64], a2 = ir[lane + 128], a3 = ir[lane + 192];
    for (int ob = 0; ob < 32; ob += 2) {
        int o0 = wv * 32 + ob, o1 = o0 + 1;
        const float* w0 = wl2 + (size_t)o0 * 256;
        const float* w1 = wl2 + (size_t)o1 * 256;
        float s0 = a0 * w0[lane] + a1 * w0[lane + 64] + a2 * w0[lane + 128] + a3 * w0[lane + 192];
        float s1 = a0 * w1[lane] + a1 * w1[lane + 64] + a2 * w1[lane + 128] + a3 * w1[lane + 192];
#pragma unroll
        for (int off = 32; off; off >>= 1) { s0 += __shfl_down(s0, off); s1 += __shfl_down(s1, off); }
        if (lane == 0) {
            float y0 = g7[o0] * (s0 * BNS_C) + b7[o0]; L1[o0] = y0 > 0.f ? y0 : 0.2f * y0;
            float y1 = g7[o1] * (s1 * BNS_C) + b7[o1]; L1[o1] = y1 > 0.f ? y1 : 0.2f * y1;
        }
    }
    __syncthreads();
    float b0v = L1[lane], b1v = L1[lane + 64];
    for (int ob = 0; ob < 16; ob += 2) {
        int o0 = wv * 16 + ob, o1 = o0 + 1;
        const float* w0 = wl21 + (size_t)o0 * 128;
        const float* w1 = wl21 + (size_t)o1 * 128;
        float s0 = b0v * w0[lane] + b1v * w0[lane + 64];
        float s1 = b0v * w1[lane] + b1v * w1[lane + 64];
#pragma unroll
        for (int off = 32; off; off >>= 1) { s0 += __shfl_down(s0, off); s1 += __shfl_down(s1, off); }
        if (lane == 0) { L2[o0] = s0; L2[o1] = s1; }
    }
    __syncthreads();
    float c0v = L2[lane];
    for (int ob = 0; ob < 8; ob += 2) {
        int o0 = wv * 8 + ob, o1 = o0 + 1;
        float s0 = c0v * wl22[(size_t)o0 * 64 + lane];
        float s1 = c0v * wl22[(size_t)o1 * 64 + lane];
#pragma unroll
        for (int off = 32; off; off >>= 1) { s0 += __shfl_down(s0, off); s1 += __shfl_down(s1, off); }
        if (lane == 0) {
            float y0 = g8[o0] * (s0 * BNS_C) + b8[o0];
            L3[o0] = 0.5f * y0 * (1.f + erff(y0 * 0.70710678118654752f));
            float y1 = g8[o1] * (s1 * BNS_C) + b8[o1];
            L3[o1] = 0.5f * y1 * (1.f + erff(y1 * 0.70710678118654752f));
        }
    }
    __syncthreads();
    float d0v = (lane < 32) ? L3[lane] : 0.f;
    for (int o = wv; o < 90; o += 4) {
        float s = (lane < 32) ? d0v * wl3[(size_t)o * 32 + lane] : 0.f;
#pragma unroll
        for (int off = 32; off; off >>= 1) s += __shfl_down(s, off);
        if (lane == 0) out[r * 90 + o] = s;
    }
}

extern "C" void kernel_launch(void* const* d_in, const int* in_sizes, int n_in,
                              void* d_out, int out_size, void* d_ws, size_t ws_size,
                              hipStream_t stream) {
    typedef const float* fp;
    fp x  = (fp)d_in[0];
    fp w1 = (fp)d_in[2],  g1 = (fp)d_in[3],  b1 = (fp)d_in[4];
    fp w2 = (fp)d_in[5],  g2 = (fp)d_in[6],  b2 = (fp)d_in[7];
    fp w3 = (fp)d_in[8],  g3 = (fp)d_in[9],  b3 = (fp)d_in[10];
    fp w4 = (fp)d_in[11], g4 = (fp)d_in[12], b4 = (fp)d_in[13];
    fp w5 = (fp)d_in[14], g5 = (fp)d_in[15], b5 = (fp)d_in[16];
    fp wl1 = (fp)d_in[17], g6 = (fp)d_in[18], b6 = (fp)d_in[19];
    fp wl2 = (fp)d_in[20], g7 = (fp)d_in[21], b7 = (fp)d_in[22];
    fp wl21 = (fp)d_in[23], wl22 = (fp)d_in[24];
    fp g8 = (fp)d_in[25], b8 = (fp)d_in[26], wl3 = (fp)d_in[27];

    char* ws = (char*)d_ws;
    size_t off = 0;
    auto alloc = [&](size_t floats) { float* p_ = (float*)(ws + off); off += floats * 4; off = (off + 255) & ~(size_t)255; return p_; };
    float* X0  = alloc(131072);       // 16*1024*8
    float* X1  = alloc(1048576);      // [b][n][64]
    float* X2  = alloc(1048576);
    float* X3  = alloc(2097152);      // [b][n][128]
    float* xx  = alloc(16384);
    int*   nbr = (int*)alloc(327680); // 16*1024*20
    unsigned short* HB = (unsigned short*)alloc(4194304);  // bf16 k-sliced [b][s][n][32]
    unsigned short* W5B = (unsigned short*)alloc(262144);  // bf16 [1024][512]
    float* pp  = alloc(262144);       // 8 row-block partials x 16 b x 2048
    float* z1  = alloc(4096);
    float* V   = alloc(4194304);      // [b][n][256] max
    float* U   = alloc(4194304);

    k_xin_t<<<64, 256, 0, stream>>>(x, X0, xx);
    k_w5b<<<256, 256, 0, stream>>>(w5, W5B);

    struct Blk { const float* Xin; int Cp, C, O, Olog, coff; const float *w, *g, *b; float* Xout; };
    Blk blks[4] = {
        {X0, 8,   6,   64,  6, 0,   w1, g1, b1, X1},
        {X1, 64,  64,  64,  6, 64,  w2, g2, b2, X2},
        {X2, 64,  64,  128, 7, 128, w3, g3, b3, X3},
        {X3, 128, 128, 256, 8, 256, w4, g4, b4, (float*)0},   // X4 never read: HB carries it
    };
    for (int i = 0; i < 4; ++i) {
        const Blk& B_ = blks[i];
        k_gtk<<<1024, 256, 0, stream>>>(B_.Xin, xx, nbr, B_.Cp);
        k_uv<<<dim3(16, B_.O / 64, 16), 256, 0, stream>>>(B_.Xin, B_.w, V, U, B_.Cp, B_.C, B_.O);
        k_gmax4<<<16 * B_.O, 256, 0, stream>>>(V, U, nbr, B_.g, B_.b, B_.Xout, xx, HB, B_.coff, B_.O, B_.Olog);
    }

    k_final_mfma<<<dim3(128, 8, 1), 256, 0, stream>>>(HB, W5B, g5, b5, pp);

    k_fc2p<<<(16 * 256) / 4, 256, 0, stream>>>(pp, wl1, g6, b6, z1, 256);
    k_fc_tail<<<16, 256, 0, stream>>>(z1, wl2, g7, b7, wl21, wl22, g8, b8, wl3, (float*)d_out);
}

// Round 12
// 536.346 us; speedup vs baseline: 1.3715x; 1.3715x over previous
//
#include <hip/hip_runtime.h>
#include <math.h>
#include <float.h>

#define BNS_C 0.9999950000374996f /* 1/sqrt(1+1e-5) */

typedef __bf16 bf8 __attribute__((ext_vector_type(8)));
typedef float f4 __attribute__((ext_vector_type(4)));
union I4BF8 { int4 i; bf8 b; };

static __device__ __forceinline__ unsigned short f2bf(float f) {
    unsigned u = __float_as_uint(f);
    u += 0x7fff + ((u >> 16) & 1);          // round-to-nearest-even
    return (unsigned short)(u >> 16);
}

// ------- x[b][6][1024] -> X0[b][n][8] (zero-padded) + xx norms -------
__global__ void k_xin_t(const float* __restrict__ x, float* __restrict__ X0, float* __restrict__ xx) {
    int i = blockIdx.x * 256 + threadIdx.x;   // over 16384 points
    int b = i >> 10, n = i & 1023;
    const float* xb = x + (((size_t)b * 6) << 10) + n;
    float4* o4 = (float4*)(X0 + ((size_t)i << 3));
    float v0 = xb[0], v1 = xb[1 << 10], v2 = xb[2 << 10];
    float v3 = xb[3 << 10], v4 = xb[4 << 10], v5 = xb[5 << 10];
    o4[0] = make_float4(v0, v1, v2, v3);
    o4[1] = make_float4(v4, v5, 0.f, 0.f);
    xx[i] = v0*v0 + v1*v1 + v2*v2 + v3*v3 + v4*v4 + v5*v5;
}

// ------- w5 f32 [1024][512] -> bf16 [1024][512] (once per launch) -------
__global__ void k_w5b(const float* __restrict__ w5, unsigned short* __restrict__ W5B) {
    int i = blockIdx.x * 256 + threadIdx.x;   // 65536 threads x 8 floats
    const float4* src = (const float4*)(w5 + (size_t)i * 8);
    float4 f0 = src[0], f1 = src[1];
    I4BF8 u_;
    u_.i.x = f2bf(f0.x) | ((unsigned)f2bf(f0.y) << 16);
    u_.i.y = f2bf(f0.z) | ((unsigned)f2bf(f0.w) << 16);
    u_.i.z = f2bf(f1.x) | ((unsigned)f2bf(f1.y) << 16);
    u_.i.w = f2bf(f1.z) | ((unsigned)f2bf(f1.w) << 16);
    *(int4*)(W5B + (size_t)i * 8) = u_.i;
}

// ---- SYMMETRIC gram (64x64 triangle tiles, 136/batch) + REGISTER PREFETCH ----
// r7: bigger tiles tank occupancy (latency hiding needs the wide grid).
// r9/r11: fusing topk in is latency-bound disaster (178us/dispatch) — keep split.
// Staging map identical to the old e-loop (cc=tid&31, row=tid>>5+8k) -> bit-identical D.
__global__ __launch_bounds__(256) void k_gram2s(const float* __restrict__ X, const float* __restrict__ xx,
                                                float* __restrict__ D, int Cp, int b0) {
    int z = blockIdx.z, b = b0 + z;
    int t = blockIdx.x;                      // 0..135 upper-triangle tile id
    int i = 0, rem = t;
    while (rem >= 16 - i) { rem -= 16 - i; ++i; }
    int j = i + rem;                         // j >= i
    int n0 = i << 6, m0 = j << 6;
    __shared__ float As[32 * 68], Bs[32 * 68];   // [cc][row]
    int tid = threadIdx.x;
    int ti = tid & 15, tj = tid >> 4;
    int scc = tid & 31, srow = tid >> 5;     // staging: fixed cc per lane, rows srow+8k
    float acc[4][4] = {};
    float pa[8], pb[8];
    const float* Xb = X + (((size_t)b) << 10) * Cp;
    int nIter = (Cp + 31) >> 5;

    {   // prefetch K-slice 0
        int c = scc;
        bool cv = (c < Cp);
        const float* An = Xb + (size_t)(n0 + srow) * Cp + c;
        const float* Bm = Xb + (size_t)(m0 + srow) * Cp + c;
#pragma unroll
        for (int k2 = 0; k2 < 8; ++k2) {
            pa[k2] = cv ? An[(size_t)(k2 * 8) * Cp] : 0.f;
            pb[k2] = cv ? Bm[(size_t)(k2 * 8) * Cp] : 0.f;
        }
    }
    for (int it = 0; it < nIter; ++it) {
        __syncthreads();                     // prev iter's ds_reads done
#pragma unroll
        for (int k2 = 0; k2 < 8; ++k2) {
            As[scc * 68 + k2 * 8 + srow] = pa[k2];
            Bs[scc * 68 + k2 * 8 + srow] = pb[k2];
        }
        __syncthreads();                     // tile visible
        if (it + 1 < nIter) {                // prefetch next K-slice under the FMA block
            int c = ((it + 1) << 5) + scc;
            bool cv = (c < Cp);
            const float* An = Xb + (size_t)(n0 + srow) * Cp + c;
            const float* Bm = Xb + (size_t)(m0 + srow) * Cp + c;
#pragma unroll
            for (int k2 = 0; k2 < 8; ++k2) {
                pa[k2] = cv ? An[(size_t)(k2 * 8) * Cp] : 0.f;
                pb[k2] = cv ? Bm[(size_t)(k2 * 8) * Cp] : 0.f;
            }
        }
#pragma unroll 8
        for (int cc = 0; cc < 32; ++cc) {
            const float4 av = *(const float4*)(As + cc * 68 + 4 * tj);
            const float4 bv = *(const float4*)(Bs + cc * 68 + 4 * ti);
            acc[0][0] += av.x * bv.x; acc[0][1] += av.x * bv.y; acc[0][2] += av.x * bv.z; acc[0][3] += av.x * bv.w;
            acc[1][0] += av.y * bv.x; acc[1][1] += av.y * bv.y; acc[1][2] += av.y * bv.z; acc[1][3] += av.y * bv.w;
            acc[2][0] += av.z * bv.x; acc[2][1] += av.z * bv.y; acc[2][2] += av.z * bv.z; acc[2][3] += av.z * bv.w;
            acc[3][0] += av.w * bv.x; acc[3][1] += av.w * bv.y; acc[3][2] += av.w * bv.z; acc[3][3] += av.w * bv.w;
        }
    }
    const float4 xm = *(const float4*)(xx + (b << 10) + m0 + 4 * ti);
    const float4 xn4 = *(const float4*)(xx + (b << 10) + n0 + 4 * tj);
    // direct tile: rows n (row-norm first)
#pragma unroll
    for (int a = 0; a < 4; ++a) {
        int n = n0 + 4 * tj + a;
        float xn = (a == 0) ? xn4.x : (a == 1) ? xn4.y : (a == 2) ? xn4.z : xn4.w;
        float4 o;
        o.x = (2.f * acc[a][0] - xn) - xm.x;
        o.y = (2.f * acc[a][1] - xn) - xm.y;
        o.z = (2.f * acc[a][2] - xn) - xm.z;
        o.w = (2.f * acc[a][3] - xn) - xm.w;
        *(float4*)(D + ((size_t)((z << 10) + n) << 10) + m0 + 4 * ti) = o;
    }
    // transposed tile: rows m (row-norm first) — direct float4 global stores
    if (i != j) {
#pragma unroll
        for (int k = 0; k < 4; ++k) {
            float xmk = (k == 0) ? xm.x : (k == 1) ? xm.y : (k == 2) ? xm.z : xm.w;
            float4 o2;
            o2.x = (2.f * acc[0][k] - xmk) - xn4.x;
            o2.y = (2.f * acc[1][k] - xmk) - xn4.y;
            o2.z = (2.f * acc[2][k] - xmk) - xn4.z;
            o2.w = (2.f * acc[3][k] - xmk) - xn4.w;
            *(float4*)(D + ((size_t)((z << 10) + m0 + 4 * ti + k) << 10) + n0 + 4 * tj) = o2;
        }
    }
}

// ---- top-20 per row via RADIX SELECT (set semantics; downstream max is order-invariant) ----
#define WSYNC() asm volatile("s_waitcnt lgkmcnt(0)" ::: "memory")
__global__ __launch_bounds__(256) void k_topk(const float* __restrict__ D, int* __restrict__ idxo, int b0) {
    __shared__ unsigned int H[4][256 * 4];   // per-wave 4-replica histogram, 16 KB
    __shared__ int CNT[4];
    int lane = threadIdx.x & 63, wv = threadIdx.x >> 6;
    int rl = blockIdx.x * 4 + wv;
    const float4* row4 = (const float4*)(D + ((size_t)rl << 10));
    unsigned int* Hw = H[wv];
    int rep = (lane & 3);

    unsigned long long kk[16];
#pragma unroll
    for (int j = 0; j < 4; ++j) {
        float4 v = row4[lane + 64 * j];
#pragma unroll
        for (int i = 0; i < 4; ++i) {
            float f = (i == 0) ? v.x : (i == 1) ? v.y : (i == 2) ? v.z : v.w;
            unsigned u = __float_as_uint(f);
            unsigned s = u ^ ((unsigned)(((int)u) >> 31) | 0x80000000u);
            int m = 4 * lane + 256 * j + i;
            kk[j * 4 + i] = ((unsigned long long)s << 32) | (unsigned)(1023 - m);
        }
    }

    unsigned long long pfx = 0;
    int shift = 56, kneed = 20;
    unsigned long long thresh = 0; int tshift = 0;
    for (;;) {
#pragma unroll
        for (int z = 0; z < 16; ++z) Hw[lane + 64 * z] = 0u;
        WSYNC();
        if (shift == 56) {
#pragma unroll
            for (int j = 0; j < 16; ++j)
                atomicAdd(&Hw[(((unsigned)(kk[j] >> 56)) & 255u) * 4 + rep], 1u);
        } else {
#pragma unroll
            for (int j = 0; j < 16; ++j)
                if ((kk[j] >> (shift + 8)) == pfx)
                    atomicAdd(&Hw[(((unsigned)(kk[j] >> shift)) & 255u) * 4 + rep], 1u);
        }
        WSYNC();
        int bTop = 255 - 4 * lane;
        uint4 r0 = *(const uint4*)(Hw + (bTop    ) * 4);
        uint4 r1 = *(const uint4*)(Hw + (bTop - 1) * 4);
        uint4 r2 = *(const uint4*)(Hw + (bTop - 2) * 4);
        uint4 r3 = *(const uint4*)(Hw + (bTop - 3) * 4);
        int h0 = (int)(r0.x + r0.y + r0.z + r0.w);
        int h1 = (int)(r1.x + r1.y + r1.z + r1.w);
        int h2 = (int)(r2.x + r2.y + r2.z + r2.w);
        int h3 = (int)(r3.x + r3.y + r3.z + r3.w);
        int s4 = h0 + h1 + h2 + h3;
        int inc = s4;
#pragma unroll
        for (int off = 1; off < 64; off <<= 1) {
            int y = __shfl_up(inc, off);
            if (lane >= off) inc += y;
        }
        int pre = inc - s4;
        bool qual = (pre < kneed) && (inc >= kneed);
        unsigned long long qm = __ballot(qual);
        int src = __ffsll((unsigned long long)qm) - 1;
        int bsel = 0, above = 0, cntb = 0;
        if (qual) {
            int c1 = pre + h0, c2 = c1 + h1, c3 = c2 + h2;
            if (c1 >= kneed)      { bsel = bTop;     above = pre; cntb = h0; }
            else if (c2 >= kneed) { bsel = bTop - 1; above = c1;  cntb = h1; }
            else if (c3 >= kneed) { bsel = bTop - 2; above = c2;  cntb = h2; }
            else                  { bsel = bTop - 3; above = c3;  cntb = h3; }
        }
        bsel  = __shfl(bsel, src);
        above = __shfl(above, src);
        cntb  = __shfl(cntb, src);
        if (above + cntb == kneed) {
            thresh = (pfx << 8) | (unsigned)bsel;
            tshift = shift;
            break;
        }
        kneed -= above;
        pfx = (pfx << 8) | (unsigned)bsel;
        shift -= 8;
    }
    if (lane == 0) CNT[wv] = 0;
    WSYNC();
    int* outp = idxo + (size_t)((b0 << 10) + rl) * 20;
#pragma unroll
    for (int j = 0; j < 16; ++j) {
        if ((kk[j] >> tshift) >= thresh) {
            int p = atomicAdd(&CNT[wv], 1);
            outp[p] = 1023 - (int)(kk[j] & 1023u);
        }
    }
}
#undef WSYNC

// ---- V[b][n][o] = X·Wa^T, U[b][n][o] = X·(Wb-Wa)^T ; c-major LDS + reg prefetch ----
__global__ __launch_bounds__(256) void k_uv(const float* __restrict__ X, const float* __restrict__ w,
                                            float* __restrict__ V, float* __restrict__ U,
                                            int Cp, int C, int O) {
    int n0 = blockIdx.x * 64, o0 = blockIdx.y * 64, b = blockIdx.z;
    __shared__ float Xs[32 * 68], Was[32 * 68], Wds[32 * 68];
    int tid = threadIdx.x, ti = tid & 15, tj = tid >> 4;
    int scc = tid & 31, srow = tid >> 5;
    float accv[4][4] = {}, accu[4][4] = {};
    float px[8], pwa[8], pwd[8];
    const float* Xb = X + (((size_t)b) << 10) * Cp;
    int W2 = 2 * C;

    {   // prefetch K-slice 0
        int c = scc;
        const float* Xn = Xb + (size_t)(n0 + srow) * Cp + c;
        const float* Wr = w + (size_t)(o0 + srow) * W2 + c;
#pragma unroll
        for (int k2 = 0; k2 < 8; ++k2) {
            px[k2] = (c < Cp) ? Xn[(size_t)(k2 * 8) * Cp] : 0.f;
            float wa = 0.f, wd = 0.f;
            if (c < C) {
                float a_ = Wr[(size_t)(k2 * 8) * W2];
                float b_ = Wr[(size_t)(k2 * 8) * W2 + C];
                wa = a_; wd = b_ - a_;
            }
            pwa[k2] = wa; pwd[k2] = wd;
        }
    }
    for (int c0 = 0; c0 < Cp; c0 += 32) {
        __syncthreads();
#pragma unroll
        for (int k2 = 0; k2 < 8; ++k2) {
            Xs[scc * 68 + k2 * 8 + srow]  = px[k2];
            Was[scc * 68 + k2 * 8 + srow] = pwa[k2];
            Wds[scc * 68 + k2 * 8 + srow] = pwd[k2];
        }
        __syncthreads();
        if (c0 + 32 < Cp) {                  // prefetch next K-slice under the FMA block
            int c = c0 + 32 + scc;
            const float* Xn = Xb + (size_t)(n0 + srow) * Cp + c;
            const float* Wr = w + (size_t)(o0 + srow) * W2 + c;
#pragma unroll
            for (int k2 = 0; k2 < 8; ++k2) {
                px[k2] = (c < Cp) ? Xn[(size_t)(k2 * 8) * Cp] : 0.f;
                float wa = 0.f, wd = 0.f;
                if (c < C) {
                    float a_ = Wr[(size_t)(k2 * 8) * W2];
                    float b_ = Wr[(size_t)(k2 * 8) * W2 + C];
                    wa = a_; wd = b_ - a_;
                }
                pwa[k2] = wa; pwd[k2] = wd;
            }
        }
#pragma unroll 8
        for (int cc = 0; cc < 32; ++cc) {
            const float4 xv = *(const float4*)(Xs  + cc * 68 + 4 * tj);
            const float4 av = *(const float4*)(Was + cc * 68 + 4 * ti);
            const float4 dv = *(const float4*)(Wds + cc * 68 + 4 * ti);
            accv[0][0] += xv.x * av.x; accv[0][1] += xv.x * av.y; accv[0][2] += xv.x * av.z; accv[0][3] += xv.x * av.w;
            accv[1][0] += xv.y * av.x; accv[1][1] += xv.y * av.y; accv[1][2] += xv.y * av.z; accv[1][3] += xv.y * av.w;
            accv[2][0] += xv.z * av.x; accv[2][1] += xv.z * av.y; accv[2][2] += xv.z * av.z; accv[2][3] += xv.z * av.w;
            accv[3][0] += xv.w * av.x; accv[3][1] += xv.w * av.y; accv[3][2] += xv.w * av.z; accv[3][3] += xv.w * av.w;
            accu[0][0] += xv.x * dv.x; accu[0][1] += xv.x * dv.y; accu[0][2] += xv.x * dv.z; accu[0][3] += xv.x * dv.w;
            accu[1][0] += xv.y * dv.x; accu[1][1] += xv.y * dv.y; accu[1][2] += xv.y * dv.z; accu[1][3] += xv.y * dv.w;
            accu[2][0] += xv.z * dv.x; accu[2][1] += xv.z * dv.y; accu[2][2] += xv.z * dv.z; accu[2][3] += xv.z * dv.w;
            accu[3][0] += xv.w * dv.x; accu[3][1] += xv.w * dv.y; accu[3][2] += xv.w * dv.z; accu[3][3] += xv.w * dv.w;
        }
    }
#pragma unroll
    for (int a = 0; a < 4; ++a) {
        int n = n0 + 4 * tj + a;
        size_t base = ((size_t)((b << 10) + n)) * O + o0 + 4 * ti;
        *(float4*)(V + base) = make_float4(accv[a][0], accv[a][1], accv[a][2], accv[a][3]);
        *(float4*)(U + base) = make_float4(accu[a][0], accu[a][1], accu[a][2], accu[a][3]);
    }
}

// ---- float4-vectorized gmax: out[b][n][o] = max_k leaky(bn(V[m_k]+U[n])) ----
__global__ __launch_bounds__(256) void k_gmax4(const float* __restrict__ V, const float* __restrict__ U,
                                               const int* __restrict__ idx,
                                               const float* __restrict__ gg, const float* __restrict__ bb,
                                               float* __restrict__ Xo, float* __restrict__ xx,
                                               unsigned short* __restrict__ HB, int coff, int O, int Olog) {
    int tid = threadIdx.x;
    int L = O >> 2;                          // lanes per point
    int j = tid >> (Olog - 2);               // point slot in block
    int o4 = tid & (L - 1);
    int o = o4 << 2;
    int orig = blockIdx.x;                   // 16*O blocks
    int r = orig >> 3;
    int b = (orig & 7) + ((r >> Olog) << 3); // XCD class = b & 7
    int pg = r & ((1 << Olog) - 1);
    int n = (pg << (10 - Olog)) + j;
    int pt = (b << 10) + n;

    float4 uv = *(const float4*)(U + (size_t)pt * O + o);
    float4 gv = *(const float4*)(gg + o);
    float4 bv = *(const float4*)(bb + o);
    const int* ip = idx + (size_t)pt * 20;   // 80 B, 16B-aligned
    int4 i0 = *(const int4*)(ip);
    int4 i1 = *(const int4*)(ip + 4);
    int4 i2 = *(const int4*)(ip + 8);
    int4 i3 = *(const int4*)(ip + 12);
    int4 i4 = *(const int4*)(ip + 16);
    const float4* Vb = (const float4*)(V + ((size_t)(b << 10)) * O) + o4;

    float mx0 = -FLT_MAX, mx1 = -FLT_MAX, mx2 = -FLT_MAX, mx3 = -FLT_MAX;
#define GK(M) { int m_ = (M) & 1023; float4 vv = Vb[(size_t)m_ * L]; float y_; \
    y_ = gv.x * ((vv.x + uv.x) * BNS_C) + bv.x; y_ = fmaxf(y_, 0.2f * y_); mx0 = fmaxf(mx0, y_); \
    y_ = gv.y * ((vv.y + uv.y) * BNS_C) + bv.y; y_ = fmaxf(y_, 0.2f * y_); mx1 = fmaxf(mx1, y_); \
    y_ = gv.z * ((vv.z + uv.z) * BNS_C) + bv.z; y_ = fmaxf(y_, 0.2f * y_); mx2 = fmaxf(mx2, y_); \
    y_ = gv.w * ((vv.w + uv.w) * BNS_C) + bv.w; y_ = fmaxf(y_, 0.2f * y_); mx3 = fmaxf(mx3, y_); }
    GK(i0.x) GK(i0.y) GK(i0.z) GK(i0.w)
    GK(i1.x) GK(i1.y) GK(i1.z) GK(i1.w)
    GK(i2.x) GK(i2.y) GK(i2.z) GK(i2.w)
    GK(i3.x) GK(i3.y) GK(i3.z) GK(i3.w)
    GK(i4.x) GK(i4.y) GK(i4.z) GK(i4.w)
#undef GK

    if (Xo) *(float4*)(Xo + (size_t)pt * O + o) = make_float4(mx0, mx1, mx2, mx3);

    int c = coff + o;                        // o % 4 == 0 -> 4 contiguous within a 32-slice
    union { int2 i2v; unsigned short u[4]; } pk;
    pk.u[0] = f2bf(mx0); pk.u[1] = f2bf(mx1); pk.u[2] = f2bf(mx2); pk.u[3] = f2bf(mx3);
    *(int2*)(HB + (((size_t)(b * 16 + (c >> 5)) << 10) + n) * 32 + (c & 31)) = pk.i2v;

    if (Xo) {
        float s = mx0 * mx0 + mx1 * mx1 + mx2 * mx2 + mx3 * mx3;
        for (int off = L >> 1; off; off >>= 1) s += __shfl_down(s, off, L);
        if (o4 == 0) xx[pt] = s;
    }
}

// ------- fused MFMA GEMM + BN/leaky + partial max/sum pool, LDS-tiled 128x128 -------
// NAMED-SCALAR register state (array forms spilled to scratch in r1-r2).
__global__ __launch_bounds__(256, 2) void k_final_mfma(const unsigned short* __restrict__ HB,
                                                       const unsigned short* __restrict__ W5B,
                                                       const float* __restrict__ g5,
                                                       const float* __restrict__ b5,
                                                       float* __restrict__ pp) {
    __shared__ __align__(16) unsigned short As[128 * 64];
    __shared__ __align__(16) unsigned short Bs[128 * 64];
    __shared__ float Lm[2][128], Ls[2][128];
    int rb = blockIdx.x;                     // 0..127 : b = rb>>3, n0 = (rb&7)*128
    int o0 = blockIdx.y << 7;                // 0..896
    int b  = rb >> 3, n0 = (rb & 7) << 7;
    int tid = threadIdx.x, lane = tid & 63, wv = tid >> 6;
    int wm = wv >> 1, wn = wv & 1;
    int wm64 = wm << 6, wn64 = wn << 6;
    int ti = lane & 15, tq = lane >> 4;
    int srow = lane >> 3;                    // 0..7 (row within 8-row segment)
    int sch  = lane & 7;                     // chunk 0..7 (8 ush = 16 B each)
    int wch  = (sch ^ srow) << 3;            // swizzled write chunk offset (ushorts)

    const unsigned short* Abase = HB + ((((size_t)(b * 16 + (sch >> 2))) << 10) + n0) * 32 + (sch & 3) * 8;
    const unsigned short* Bbase = W5B + (size_t)o0 * 512 + sch * 8;

    f4 c00 = {0.f,0.f,0.f,0.f}, c01 = c00, c02 = c00, c03 = c00;
    f4 c10 = c00, c11 = c00, c12 = c00, c13 = c00;
    f4 c20 = c00, c21 = c00, c22 = c00, c23 = c00;
    f4 c30 = c00, c31 = c00, c32 = c00, c33 = c00;

    int4 ar0, ar1, ar2, ar3, br0, br1, br2, br3;

#define PF(AR, BR, J, IT) { int rA_ = ((J) * 4 + wv) * 8 + srow; \
    AR = *(const int4*)(Abase + ((size_t)(IT) << 16) + (size_t)rA_ * 32); \
    BR = *(const int4*)(Bbase + (size_t)rA_ * 512 + (IT) * 64); }
#define ST(AR, BR, J) { int rA_ = ((J) * 4 + wv) * 8 + srow; \
    *(int4*)(As + rA_ * 64 + wch) = AR; *(int4*)(Bs + rA_ * 64 + wch) = BR; }
#define FRAG_LD(AV, BV, F) { I4BF8 uA_, uB_; \
    uA_.i = *(const int4*)(As + (wm64 + (F) * 16 + ti) * 64 + co); \
    uB_.i = *(const int4*)(Bs + (wn64 + (F) * 16 + ti) * 64 + co); \
    AV = uA_.b; BV = uB_.b; }
#define MM(CV, AV, BV) CV = __builtin_amdgcn_mfma_f32_16x16x32_bf16(AV, BV, CV, 0, 0, 0);

    PF(ar0, br0, 0, 0) PF(ar1, br1, 1, 0) PF(ar2, br2, 2, 0) PF(ar3, br3, 3, 0)
    for (int it = 0; it < 8; ++it) {
        __syncthreads();                      // prev iter's ds_reads done
        ST(ar0, br0, 0) ST(ar1, br1, 1) ST(ar2, br2, 2) ST(ar3, br3, 3)
        __syncthreads();                      // tile visible
        if (it < 7) {
            PF(ar0, br0, 0, it + 1) PF(ar1, br1, 1, it + 1)
            PF(ar2, br2, 2, it + 1) PF(ar3, br3, 3, it + 1)
        }
#pragma unroll
        for (int kk = 0; kk < 2; ++kk) {
            int co = (((kk * 4 + tq)) ^ (ti & 7)) << 3;   // swizzled read chunk
            bf8 a0, a1, a2, a3, p0, p1, p2, p3;
            FRAG_LD(a0, p0, 0) FRAG_LD(a1, p1, 1) FRAG_LD(a2, p2, 2) FRAG_LD(a3, p3, 3)
            MM(c00, a0, p0) MM(c01, a0, p1) MM(c02, a0, p2) MM(c03, a0, p3)
            MM(c10, a1, p0) MM(c11, a1, p1) MM(c12, a1, p2) MM(c13, a1, p3)
            MM(c20, a2, p0) MM(c21, a2, p1) MM(c22, a2, p2) MM(c23, a2, p3)
            MM(c30, a3, p0) MM(c31, a3, p1) MM(c32, a3, p2) MM(c33, a3, p3)
        }
    }
#undef PF
#undef ST
#undef FRAG_LD
#undef MM

    float gb0 = g5[o0 + wn64 +  0 + ti] * BNS_C, bv0 = b5[o0 + wn64 +  0 + ti];
    float gb1 = g5[o0 + wn64 + 16 + ti] * BNS_C, bv1 = b5[o0 + wn64 + 16 + ti];
    float gb2 = g5[o0 + wn64 + 32 + ti] * BNS_C, bv2 = b5[o0 + wn64 + 32 + ti];
    float gb3 = g5[o0 + wn64 + 48 + ti] * BNS_C, bv3 = b5[o0 + wn64 + 48 + ti];
    float mx0 = -FLT_MAX, mx1 = -FLT_MAX, mx2 = -FLT_MAX, mx3 = -FLT_MAX;
    float sm0 = 0.f, sm1 = 0.f, sm2 = 0.f, sm3 = 0.f;

#define EPI(CV, GB, BV, MX, SM) { \
    float y_; \
    y_ = GB * CV[0] + BV; y_ = y_ > 0.f ? y_ : 0.2f * y_; MX = fmaxf(MX, y_); SM += y_; \
    y_ = GB * CV[1] + BV; y_ = y_ > 0.f ? y_ : 0.2f * y_; MX = fmaxf(MX, y_); SM += y_; \
    y_ = GB * CV[2] + BV; y_ = y_ > 0.f ? y_ : 0.2f * y_; MX = fmaxf(MX, y_); SM += y_; \
    y_ = GB * CV[3] + BV; y_ = y_ > 0.f ? y_ : 0.2f * y_; MX = fmaxf(MX, y_); SM += y_; }

    EPI(c00, gb0, bv0, mx0, sm0) EPI(c10, gb0, bv0, mx0, sm0)
    EPI(c20, gb0, bv0, mx0, sm0) EPI(c30, gb0, bv0, mx0, sm0)
    EPI(c01, gb1, bv1, mx1, sm1) EPI(c11, gb1, bv1, mx1, sm1)
    EPI(c21, gb1, bv1, mx1, sm1) EPI(c31, gb1, bv1, mx1, sm1)
    EPI(c02, gb2, bv2, mx2, sm2) EPI(c12, gb2, bv2, mx2, sm2)
    EPI(c22, gb2, bv2, mx2, sm2) EPI(c32, gb2, bv2, mx2, sm2)
    EPI(c03, gb3, bv3, mx3, sm3) EPI(c13, gb3, bv3, mx3, sm3)
    EPI(c23, gb3, bv3, mx3, sm3) EPI(c33, gb3, bv3, mx3, sm3)
#undef EPI

#define RED(MX, SM, F) { \
    float m_ = MX, s_ = SM; \
    m_ = fmaxf(m_, __shfl_down(m_, 32)); s_ += __shfl_down(s_, 32); \
    m_ = fmaxf(m_, __shfl_down(m_, 16)); s_ += __shfl_down(s_, 16); \
    if (tq == 0) { Lm[wm][wn64 + (F) * 16 + ti] = m_; Ls[wm][wn64 + (F) * 16 + ti] = s_; } }
    RED(mx0, sm0, 0) RED(mx1, sm1, 1) RED(mx2, sm2, 2) RED(mx3, sm3, 3)
#undef RED

    __syncthreads();
    if (tid < 128) {
        float m_ = fmaxf(Lm[0][tid], Lm[1][tid]);
        float s_ = Ls[0][tid] + Ls[1][tid];
        float* pb = pp + (size_t)rb * 2048;
        pb[o0 + tid] = m_;
        pb[1024 + o0 + tid] = s_;
    }
}

// ---- wl1 FC fused with the row-block partial reduction (8 partials of 128 rows) ----
__global__ __launch_bounds__(256) void k_fc2p(const float* __restrict__ pp, const float* __restrict__ w,
                                              const float* __restrict__ gg, const float* __restrict__ bb,
                                              float* __restrict__ out, int O) {
    int gw = blockIdx.x * 4 + (threadIdx.x >> 6);
    int lane = threadIdx.x & 63;
    int r = gw / O, o = gw - r * O;
    const float* wr = w + (size_t)o * 2048;
    const float* q0 = pp + (size_t)r * 8 * 2048;
    float s = 0.f;
    for (int c = lane; c < 2048; c += 64) {
        float v;
        if (c < 1024) {
            v = q0[c];
#pragma unroll
            for (int t = 1; t < 8; ++t) v = fmaxf(v, q0[t * 2048 + c]);
        } else {
            v = 0.f;
#pragma unroll
            for (int t = 0; t < 8; ++t) v += q0[t * 2048 + c];
            v *= (1.f / 1024.f);
        }
        s += v * wr[c];
    }
#pragma unroll
    for (int off = 32; off; off >>= 1) s += __shfl_down(s, off);
    if (lane == 0) {
        float y = gg[o] * (s * BNS_C) + bb[o];
        out[gw] = y > 0.f ? y : 0.2f * y;
    }
}

// ------- FC tail: one block per batch row, wave-per-output, coalesced weight loads -------
__global__ __launch_bounds__(256) void k_fc_tail(const float* __restrict__ z1,
                                                 const float* __restrict__ wl2, const float* __restrict__ g7, const float* __restrict__ b7,
                                                 const float* __restrict__ wl21,
                                                 const float* __restrict__ wl22, const float* __restrict__ g8, const float* __restrict__ b8,
                                                 const float* __restrict__ wl3,
                                                 float* __restrict__ out) {
    __shared__ float L1[128], L2[64], L3[32];
    int r = blockIdx.x;
    int tid = threadIdx.x, lane = tid & 63, wv = tid >> 6;
    const float* ir = z1 + r * 256;
    float a0 = ir[lane], a1 = ir[lane + 64], a2 = ir[lane + 128], a3 = ir[lane + 192];
    for (int ob = 0; ob < 32; ob += 2) {
        int o0 = wv * 32 + ob, o1 = o0 + 1;
        const float* w0 = wl2 + (size_t)o0 * 256;
        const float* w1 = wl2 + (size_t)o1 * 256;
        float s0 = a0 * w0[lane] + a1 * w0[lane + 64] + a2 * w0[lane + 128] + a3 * w0[lane + 192];
        float s1 = a0 * w1[lane] + a1 * w1[lane + 64] + a2 * w1[lane + 128] + a3 * w1[lane + 192];
#pragma unroll
        for (int off = 32; off; off >>= 1) { s0 += __shfl_down(s0, off); s1 += __shfl_down(s1, off); }
        if (lane == 0) {
            float y0 = g7[o0] * (s0 * BNS_C) + b7[o0]; L1[o0] = y0 > 0.f ? y0 : 0.2f * y0;
            float y1 = g7[o1] * (s1 * BNS_C) + b7[o1]; L1[o1] = y1 > 0.f ? y1 : 0.2f * y1;
        }
    }
    __syncthreads();
    float b0v = L1[lane], b1v = L1[lane + 64];
    for (int ob = 0; ob < 16; ob += 2) {
        int o0 = wv * 16 + ob, o1 = o0 + 1;
        const float* w0 = wl21 + (size_t)o0 * 128;
        const float* w1 = wl21 + (size_t)o1 * 128;
        float s0 = b0v * w0[lane] + b1v * w0[lane + 64];
        float s1 = b0v * w1[lane] + b1v * w1[lane + 64];
#pragma unroll
        for (int off = 32; off; off >>= 1) { s0 += __shfl_down(s0, off); s1 += __shfl_down(s1, off); }
        if (lane == 0) { L2[o0] = s0; L2[o1] = s1; }
    }
    __syncthreads();
    float c0v = L2[lane];
    for (int ob = 0; ob < 8; ob += 2) {
        int o0 = wv * 8 + ob, o1 = o0 + 1;
        float s0 = c0v * wl22[(size_t)o0 * 64 + lane];
        float s1 = c0v * wl22[(size_t)o1 * 64 + lane];
#pragma unroll
        for (int off = 32; off; off >>= 1) { s0 += __shfl_down(s0, off); s1 += __shfl_down(s1, off); }
        if (lane == 0) {
            float y0 = g8[o0] * (s0 * BNS_C) + b8[o0];
            L3[o0] = 0.5f * y0 * (1.f + erff(y0 * 0.70710678118654752f));
            float y1 = g8[o1] * (s1 * BNS_C) + b8[o1];
            L3[o1] = 0.5f * y1 * (1.f + erff(y1 * 0.70710678118654752f));
        }
    }
    __syncthreads();
    float d0v = (lane < 32) ? L3[lane] : 0.f;
    for (int o = wv; o < 90; o += 4) {
        float s = (lane < 32) ? d0v * wl3[(size_t)o * 32 + lane] : 0.f;
#pragma unroll
        for (int off = 32; off; off >>= 1) s += __shfl_down(s, off);
        if (lane == 0) out[r * 90 + o] = s;
    }
}

extern "C" void kernel_launch(void* const* d_in, const int* in_sizes, int n_in,
                              void* d_out, int out_size, void* d_ws, size_t ws_size,
                              hipStream_t stream) {
    typedef const float* fp;
    fp x  = (fp)d_in[0];
    fp w1 = (fp)d_in[2],  g1 = (fp)d_in[3],  b1 = (fp)d_in[4];
    fp w2 = (fp)d_in[5],  g2 = (fp)d_in[6],  b2 = (fp)d_in[7];
    fp w3 = (fp)d_in[8],  g3 = (fp)d_in[9],  b3 = (fp)d_in[10];
    fp w4 = (fp)d_in[11], g4 = (fp)d_in[12], b4 = (fp)d_in[13];
    fp w5 = (fp)d_in[14], g5 = (fp)d_in[15], b5 = (fp)d_in[16];
    fp wl1 = (fp)d_in[17], g6 = (fp)d_in[18], b6 = (fp)d_in[19];
    fp wl2 = (fp)d_in[20], g7 = (fp)d_in[21], b7 = (fp)d_in[22];
    fp wl21 = (fp)d_in[23], wl22 = (fp)d_in[24];
    fp g8 = (fp)d_in[25], b8 = (fp)d_in[26], wl3 = (fp)d_in[27];

    char* ws = (char*)d_ws;
    size_t off = 0;
    auto alloc = [&](size_t floats) { float* p_ = (float*)(ws + off); off += floats * 4; off = (off + 255) & ~(size_t)255; return p_; };
    float* X0  = alloc(131072);       // 16*1024*8
    float* X1  = alloc(1048576);      // [b][n][64]
    float* X2  = alloc(1048576);
    float* X3  = alloc(2097152);      // [b][n][128]
    float* X4  = alloc(4194304);      // [b][n][256]
    float* xx  = alloc(16384);
    int*   nbr = (int*)alloc(327680); // 16*1024*20
    unsigned short* HB = (unsigned short*)alloc(4194304);  // bf16 k-sliced [b][s][n][32]
    unsigned short* W5B = (unsigned short*)alloc(262144);  // bf16 [1024][512]
    float* pp  = alloc(262144);       // 8 row-block partials x 16 b x 2048
    float* z1  = alloc(4096);
    // pool: union of D | V+U
    size_t poolAvail = (ws_size > off) ? (ws_size - off) / 4 : 0;
    int fullD = poolAvail >= 16777216;                 // 64 MB full distance tensor
    float* pool = alloc(fullD ? 16777216 : 8388608);

    float* D = pool;
    float* V = pool;
    float* U = pool + 4194304;

    k_xin_t<<<64, 256, 0, stream>>>(x, X0, xx);
    k_w5b<<<256, 256, 0, stream>>>(w5, W5B);

    struct Blk { const float* Xin; int Cp, C, O, Olog, coff; const float *w, *g, *b; float* Xout; };
    Blk blks[4] = {
        {X0, 8,   6,   64,  6, 0,   w1, g1, b1, X1},
        {X1, 64,  64,  64,  6, 64,  w2, g2, b2, X2},
        {X2, 64,  64,  128, 7, 128, w3, g3, b3, X3},
        {X3, 128, 128, 256, 8, 256, w4, g4, b4, (float*)0},   // X4 never read: HB carries it
    };
    for (int i = 0; i < 4; ++i) {
        const Blk& B_ = blks[i];
        if (fullD) {
            k_gram2s<<<dim3(136, 1, 16), 256, 0, stream>>>(B_.Xin, xx, D, B_.Cp, 0);
            k_topk<<<4096, 256, 0, stream>>>(D, nbr, 0);
        } else {
            for (int b0 = 0; b0 < 16; b0 += 8) {
                k_gram2s<<<dim3(136, 1, 8), 256, 0, stream>>>(B_.Xin, xx, D, B_.Cp, b0);
                k_topk<<<2048, 256, 0, stream>>>(D, nbr, b0);
            }
        }
        k_uv<<<dim3(16, B_.O / 64, 16), 256, 0, stream>>>(B_.Xin, B_.w, V, U, B_.Cp, B_.C, B_.O);
        k_gmax4<<<16 * B_.O, 256, 0, stream>>>(V, U, nbr, B_.g, B_.b, B_.Xout, xx, HB, B_.coff, B_.O, B_.Olog);
    }

    k_final_mfma<<<dim3(128, 8, 1), 256, 0, stream>>>(HB, W5B, g5, b5, pp);

    k_fc2p<<<(16 * 256) / 4, 256, 0, stream>>>(pp, wl1, g6, b6, z1, 256);
    k_fc_tail<<<16, 256, 0, stream>>>(z1, wl2, g7, b7, wl21, wl22, g8, b8, wl3, (float*)d_out);
}